// Round 13
// baseline (125.455 us; speedup 1.0000x reference)
//
#include <hip/hip_runtime.h>
#include <cstdint>

typedef _Float16 f16;
typedef _Float16 f16x8 __attribute__((ext_vector_type(8)));
typedef float    f32x4 __attribute__((ext_vector_type(4)));

static __device__ __forceinline__ uint32_t pack2(float x, float y) {
    f16 hx = (f16)x, hy = (f16)y;
    uint32_t ux = __builtin_bit_cast(unsigned short, hx);
    uint32_t uy = __builtin_bit_cast(unsigned short, hy);
    return ux | (uy << 16);
}

// Hot-loop barrier: drain LDS ops only, raw s_barrier, sched pins.
// (memory clobber would force a vmcnt(0) drain -- r11 lesson.)
static __device__ __forceinline__ void lds_barrier() {
    __builtin_amdgcn_sched_barrier(0);
    asm volatile("s_waitcnt lgkmcnt(0)");
    __builtin_amdgcn_s_barrier();
    __builtin_amdgcn_sched_barrier(0);
}

// ---------------------------------------------------------------------------
// Kernel 1 (fused transpose+gemm, one block per batch, 16-WAVE TLP):
// r7/r11/r12 all land at ~74us (2.4 TB/s) regardless of pipeline structure
// -> the bottleneck is memory DUTY CYCLE at 8 barrier-locked waves/CU
// (2 waves/SIMD).  m13's 6.3 TB/s reference uses 32 waves/CU of continuous
// loaders; m114: implicit wave TLP is what overlaps load and MFMA phases.
// This version: 1024 threads / 16 waves (4/SIMD).  Reg cap 128/thread ->
// waves split output by column half: wave (gr=g&7, gc=g>>3) owns
// rows 16gr..16gr+15 x cols 128gc..128gc+127 (pass0: 64 acc regs).
//   pass 0: rows 0..127 x all cols (+ Hermitian mirror of q1 via gc==1 waves)
//   pass 1: rows 128..255 x cols 128..255 (wave: cols 64gc quadrant halves)
// Staging: 1024 threads, same verified swizzle map (fp now 0..63, 4 rows/
// thread pass0, 2 rows pass1), depth-1 reg prefetch before lds_barrier.
// MFMA K-order per output element identical to r7 -> absmax preserved.
// ---------------------------------------------------------------------------
__global__ __launch_bounds__(1024) void k_gemm(const float* __restrict__ Are,
                                               const float* __restrict__ Aim,
                                               f16* __restrict__ AhAre,
                                               f16* __restrict__ AhAim) {
    const int tid = threadIdx.x;
    const int b = blockIdx.x;

    __shared__ __align__(16) f16 ls[2][2][256 * 32];   // [buf][Re,Im] 64KB

    const int l = tid & 63, g = tid >> 6;      // lane, wave 0..15
    const int gr = g & 7, gc = g >> 3;         // row-block, col-half
    const int lr = l & 15, lk = l >> 4;

    // staging decomposition: u = m-pair 0..15, fp = col-group 0..63
    const int u = tid & 15;
    const int fp = tid >> 4;
    const int su = u >> 2, uq = u & 3;

    f16* oR = AhAre + (size_t)b * 65536;
    f16* oI = AhAim + (size_t)b * 65536;

    // ======================= PASS 0: rows 0..127, full width ================
    {
        f32x4 cR[8], cI[8];
#pragma unroll
        for (int j = 0; j < 8; ++j) { cR[j] = (f32x4)0.0f; cI[j] = (f32x4)0.0f; }

        // prologue: tile 0.  Each thread: 4 n-cols (fp*4..+3) x m-pair 2u.
        float4 v[2][2];
#pragma unroll
        for (int t = 0; t < 2; ++t) {
            const float* sp = (t ? Aim : Are) + (size_t)b * 65536
                            + (size_t)(2 * u) * 256 + fp * 4;
            v[t][0] = *(const float4*)(sp);
            v[t][1] = *(const float4*)(sp + 256);
        }

#pragma unroll
        for (int step = 0; step < 8; ++step) {
            const int p = step & 1;

            // pack -> LDS[p] (verified swizzle: word (r,s,uq), s=su^((r>>1)&3))
#pragma unroll
            for (int t = 0; t < 2; ++t) {
                float xv[4] = {v[t][0].x, v[t][0].y, v[t][0].z, v[t][0].w};
                float yv[4] = {v[t][1].x, v[t][1].y, v[t][1].z, v[t][1].w};
                uint32_t* lw = (uint32_t*)&ls[p][t][0];
#pragma unroll
                for (int i = 0; i < 4; ++i) {
                    int r = fp * 4 + i;
                    int s = su ^ ((r >> 1) & 3);
                    lw[r * 16 + s * 4 + uq] = pack2(xv[i], yv[i]);
                }
            }

            // depth-1 prefetch (reg dest; stays in flight across lds_barrier)
            if (step < 7) {
                const int m0n = 32 * (step + 1);
#pragma unroll
                for (int t = 0; t < 2; ++t) {
                    const float* sp = (t ? Aim : Are) + (size_t)b * 65536
                                    + (size_t)(m0n + 2 * u) * 256 + fp * 4;
                    v[t][0] = *(const float4*)(sp);
                    v[t][1] = *(const float4*)(sp + 256);
                }
            }

            lds_barrier();

            const f16* lsR = &ls[p][0][0];
            const f16* lsI = &ls[p][1][0];

            const int r1 = 16 * gr + lr;                // 0..127
            const int s1 = lk ^ ((r1 >> 1) & 3);
            f16x8 a1re = *(const f16x8*)(&lsR[r1 * 32 + s1 * 8]);
            uint4 u1   = *(const uint4*)(&lsI[r1 * 32 + s1 * 8]);
            f16x8 a1im = __builtin_bit_cast(f16x8, u1);
            uint4 n1 = make_uint4(u1.x ^ 0x80008000u, u1.y ^ 0x80008000u,
                                  u1.z ^ 0x80008000u, u1.w ^ 0x80008000u);
            f16x8 na1 = __builtin_bit_cast(f16x8, n1);

#pragma unroll
            for (int j = 0; j < 8; ++j) {
                int rb = 128 * gc + 16 * j + lr;        // this wave's col half
                int sb = lk ^ ((rb >> 1) & 3);
                f16x8 bre = *(const f16x8*)(&lsR[rb * 32 + sb * 8]);
                f16x8 bim = *(const f16x8*)(&lsI[rb * 32 + sb * 8]);
                cR[j] = __builtin_amdgcn_mfma_f32_16x16x32_f16(a1re, bre, cR[j], 0, 0, 0);
                cR[j] = __builtin_amdgcn_mfma_f32_16x16x32_f16(a1im, bim, cR[j], 0, 0, 0);
                cI[j] = __builtin_amdgcn_mfma_f32_16x16x32_f16(a1re, bim, cI[j], 0, 0, 0);
                cI[j] = __builtin_amdgcn_mfma_f32_16x16x32_f16(na1,  bre, cI[j], 0, 0, 0);
            }
        }

        // ---- pass-0 epilogue: rows 16gr, cols 128gc..128gc+127
#pragma unroll
        for (int j = 0; j < 8; ++j)
#pragma unroll
            for (int r = 0; r < 4; ++r) {
                int n = 16 * gr + lk * 4 + r;
                int c = 128 * gc + 16 * j + lr;
                oR[(size_t)n * 256 + c] = (f16)cR[j][r];
                oI[(size_t)n * 256 + c] = (f16)cI[j][r];
            }

        // ---- Hermitian mirror: q2[128+jj][nn] = conj(q1[nn][128+jj]).
        // q1 (rows 0..127, cols 128..255) is held by the gc==1 waves.
        f16* lsm = &ls[0][0][0];                    // reuse 32KB as [128][128]
        const int jjo = tid >> 3, q8 = tid & 7;     // 128 rows x 8 chunks

        __syncthreads();                            // all ls reads done
        // Re plane
        if (gc == 1) {
#pragma unroll
            for (int j = 0; j < 8; ++j)
#pragma unroll
                for (int r = 0; r < 4; ++r) {
                    int jj = 16 * j + lr;           // global col - 128
                    int nn = 16 * gr + lk * 4 + r;
                    lsm[jj * 128 + nn] = (f16)cR[j][r];
                }
        }
        __syncthreads();
        {
            const f16* srow = lsm + jjo * 128 + q8 * 16;
            f16* drow = oR + (size_t)(128 + jjo) * 256 + q8 * 16;
            *(uint4*)(void*)(drow)     = *(const uint4*)(srow);
            *(uint4*)(void*)(drow + 8) = *(const uint4*)(srow + 8);
        }
        __syncthreads();
        // Im plane (negated)
        if (gc == 1) {
#pragma unroll
            for (int j = 0; j < 8; ++j)
#pragma unroll
                for (int r = 0; r < 4; ++r) {
                    int jj = 16 * j + lr;
                    int nn = 16 * gr + lk * 4 + r;
                    lsm[jj * 128 + nn] = (f16)(-cI[j][r]);
                }
        }
        __syncthreads();
        {
            const f16* srow = lsm + jjo * 128 + q8 * 16;
            f16* drow = oI + (size_t)(128 + jjo) * 256 + q8 * 16;
            *(uint4*)(void*)(drow)     = *(const uint4*)(srow);
            *(uint4*)(void*)(drow + 8) = *(const uint4*)(srow + 8);
        }
        __syncthreads();                            // protect ls for pass 1
    }

    // =============== PASS 1: rows 128..255, cols 128..255 ===================
    {
        f32x4 dR[4], dI[4];
#pragma unroll
        for (int j = 0; j < 4; ++j) { dR[j] = (f32x4)0.0f; dI[j] = (f32x4)0.0f; }

        // stage cols(n) 128..255 local 0..127: 2 n's/thread (fp*2+i), m-pair 2u
        float2 w[2][2];
#pragma unroll
        for (int t = 0; t < 2; ++t) {
            const float* sp = (t ? Aim : Are) + (size_t)b * 65536
                            + (size_t)(2 * u) * 256 + 128 + fp * 2;
            w[t][0] = *(const float2*)(sp);
            w[t][1] = *(const float2*)(sp + 256);
        }

#pragma unroll
        for (int step = 0; step < 8; ++step) {
            const int p = step & 1;

#pragma unroll
            for (int t = 0; t < 2; ++t) {
                float xv[2] = {w[t][0].x, w[t][0].y};
                float yv[2] = {w[t][1].x, w[t][1].y};
                uint32_t* lw = (uint32_t*)&ls[p][t][0];
#pragma unroll
                for (int i = 0; i < 2; ++i) {
                    int r = fp * 2 + i;                 // local n (0..127)
                    int s = su ^ ((r >> 1) & 3);
                    lw[r * 16 + s * 4 + uq] = pack2(xv[i], yv[i]);
                }
            }

            if (step < 7) {
                const int m0n = 32 * (step + 1);
#pragma unroll
                for (int t = 0; t < 2; ++t) {
                    const float* sp = (t ? Aim : Are) + (size_t)b * 65536
                                    + (size_t)(m0n + 2 * u) * 256 + 128 + fp * 2;
                    w[t][0] = *(const float2*)(sp);
                    w[t][1] = *(const float2*)(sp + 256);
                }
            }

            lds_barrier();

            const f16* lsR = &ls[p][0][0];
            const f16* lsI = &ls[p][1][0];

            const int r2 = 16 * gr + lr;                // local row (gl-128)
            const int s2 = lk ^ ((r2 >> 1) & 3);
            f16x8 a2re = *(const f16x8*)(&lsR[r2 * 32 + s2 * 8]);
            uint4 u2   = *(const uint4*)(&lsI[r2 * 32 + s2 * 8]);
            f16x8 a2im = __builtin_bit_cast(f16x8, u2);
            uint4 n2 = make_uint4(u2.x ^ 0x80008000u, u2.y ^ 0x80008000u,
                                  u2.z ^ 0x80008000u, u2.w ^ 0x80008000u);
            f16x8 na2 = __builtin_bit_cast(f16x8, n2);

#pragma unroll
            for (int j = 0; j < 4; ++j) {
                int rb = 64 * gc + 16 * j + lr;         // local col
                int sb = lk ^ ((rb >> 1) & 3);
                f16x8 bre = *(const f16x8*)(&lsR[rb * 32 + sb * 8]);
                f16x8 bim = *(const f16x8*)(&lsI[rb * 32 + sb * 8]);
                dR[j] = __builtin_amdgcn_mfma_f32_16x16x32_f16(a2re, bre, dR[j], 0, 0, 0);
                dR[j] = __builtin_amdgcn_mfma_f32_16x16x32_f16(a2im, bim, dR[j], 0, 0, 0);
                dI[j] = __builtin_amdgcn_mfma_f32_16x16x32_f16(a2re, bim, dI[j], 0, 0, 0);
                dI[j] = __builtin_amdgcn_mfma_f32_16x16x32_f16(na2,  bre, dI[j], 0, 0, 0);
            }
        }

        // pass-1 epilogue: rows 128+16gr, cols 128+64gc+16j+lr
#pragma unroll
        for (int j = 0; j < 4; ++j)
#pragma unroll
            for (int r = 0; r < 4; ++r) {
                int n = 128 + 16 * gr + lk * 4 + r;
                int c = 128 + 64 * gc + 16 * j + lr;
                oR[(size_t)n * 256 + c] = (f16)dR[j][r];
                oI[(size_t)n * 256 + c] = (f16)dI[j][r];
            }
    }
}

// ---------------------------------------------------------------------------
// Kernel 2: power iteration, 8-WAVE / 32-ROWS-PER-WAVE form (unchanged:
// ~26us).  Deferred normalization (stable form).
// ---------------------------------------------------------------------------
static __device__ __forceinline__ void matvec2(const f16x8 (&afr)[2][16],
                                               const f16* __restrict__ vs, int h,
                                               float4 (&y)[2]) {
    f16x8 bf[16];
#pragma unroll
    for (int c = 0; c < 16; ++c) bf[c] = *(const f16x8*)(vs + 32 * c + 8 * h);
    f32x4 P0[2], P1[2];
#pragma unroll
    for (int rg = 0; rg < 2; ++rg) { P0[rg] = (f32x4)0.0f; P1[rg] = (f32x4)0.0f; }
#pragma unroll
    for (int c = 0; c < 16; ++c) {
#pragma unroll
        for (int rg = 0; rg < 2; ++rg) {
            if (c & 1) P1[rg] = __builtin_amdgcn_mfma_f32_16x16x32_f16(afr[rg][c], bf[c], P1[rg], 0, 0, 0);
            else       P0[rg] = __builtin_amdgcn_mfma_f32_16x16x32_f16(afr[rg][c], bf[c], P0[rg], 0, 0, 0);
        }
    }
#pragma unroll
    for (int rg = 0; rg < 2; ++rg)
        y[rg] = make_float4(P0[rg][0] + P1[rg][0], P0[rg][1] + P1[rg][1],
                            P0[rg][2] + P1[rg][2], P0[rg][3] + P1[rg][3]);
}

__global__ __launch_bounds__(512, 2) void k_power(const f16* __restrict__ AhAre,
                                                  const f16* __restrict__ AhAim,
                                                  const float* __restrict__ vre,
                                                  const float* __restrict__ vim,
                                                  const int* __restrict__ pniter,
                                                  float* __restrict__ out) {
    const int tid = threadIdx.x;
    const int b = blockIdx.x;
    const int l = tid & 63;            // lane
    const int g = tid >> 6;            // wave 0..7
    const int sel = l & 15;            // A-row-within-group / B-col
    const int h = l >> 4;              // k-slot 0..3

    __shared__ __align__(16) f16 v0h[2][512];   // [buf][ vr ; -vi ]
    __shared__ __align__(16) f16 v1h[2][512];   // [buf][ vi ;  vr ]
    __shared__ __align__(16) float part[2][8];

    // ---- load A fragments: wave g owns rows 32g .. 32g+31 (2 row-groups)
    f16x8 afr[2][16];
#pragma unroll
    for (int rg = 0; rg < 2; ++rg) {
        const int m = 32 * g + 16 * rg + sel;
        const f16* bR = AhAre + (size_t)b * 65536 + (size_t)m * 256 + 8 * h;
        const f16* bI = AhAim + (size_t)b * 65536 + (size_t)m * 256 + 8 * h;
#pragma unroll
        for (int c = 0; c < 8; ++c) {
            afr[rg][c]     = *(const f16x8*)(bR + 32 * c);
            afr[rg][8 + c] = *(const f16x8*)(bI + 32 * c);
        }
    }
#pragma unroll
    for (int rg = 0; rg < 2; ++rg)
#pragma unroll
        for (int c = 0; c < 16; ++c) asm volatile("" : "+a"(afr[rg][c]));

    if (tid < 256) {
        float xr = vre[b * 256 + tid], xi = vim[b * 256 + tid];
        v0h[0][tid]       = (f16)xr;
        v0h[0][256 + tid] = (f16)(-xi);
        v1h[0][tid]       = (f16)xi;
        v1h[0][256 + tid] = (f16)xr;
    }
    __syncthreads();

    const int niter = *pniter;
    const f16* vsel = (sel == 0) ? &v0h[0][0] : &v1h[0][0];

    float eig = 0.0f;

    auto npart = [&](int wb, const float4 (&y)[2]) {
        float s_ = 0.0f;
        if (sel < 2) {
#pragma unroll
            for (int rg = 0; rg < 2; ++rg)
                s_ += y[rg].x * y[rg].x + y[rg].y * y[rg].y
                    + y[rg].z * y[rg].z + y[rg].w * y[rg].w;
        }
        s_ += __shfl_xor(s_, 1, 64);
        s_ += __shfl_xor(s_, 16, 64);
        s_ += __shfl_xor(s_, 32, 64);
        if (l == 0) part[wb][g] = s_;
    };
    auto vwrite = [&](int wb, const float4 (&y)[2], float sc) {
        if (sel < 2) {
#pragma unroll
            for (int rg = 0; rg < 2; ++rg) {
                uint32_t w0 = pack2(y[rg].x * sc, y[rg].y * sc);
                uint32_t w1 = pack2(y[rg].z * sc, y[rg].w * sc);
                int m0 = 32 * g + 16 * rg + 4 * h;    // 4 consecutive rows
                if (sel == 0) {                       // y = new vr
                    *(uint2*)(void*)(&v0h[wb][m0])       = make_uint2(w0, w1);
                    *(uint2*)(void*)(&v1h[wb][256 + m0]) = make_uint2(w0, w1);
                } else {                              // y = new vi
                    *(uint2*)(void*)(&v1h[wb][m0])       = make_uint2(w0, w1);
                    *(uint2*)(void*)(&v0h[wb][256 + m0]) =
                        make_uint2(w0 ^ 0x80008000u, w1 ^ 0x80008000u);
                }
            }
        }
    };
    auto psum = [&](int rb) -> float {
        float4 q0 = *(const float4*)(&part[rb][0]);
        float4 q1 = *(const float4*)(&part[rb][4]);
        return (q0.x + q0.y + q0.z + q0.w) + (q1.x + q1.y + q1.z + q1.w);
    };

    float sc_m1 = 1.0f;   // s_{t-1}
    float nm2   = 1.0f;   // n_{t-2}

    float4 y[2];

    // ---- peeled iteration 1 (synchronous): u_1 = y_1/e_1, n_1 = 1 ----
    if (niter >= 1) {
        matvec2(afr, vsel, h, y);
        npart(1, y);
        __syncthreads();
        float e1v = sqrtf(psum(1));
        float sc  = __builtin_amdgcn_rcpf(e1v + 1e-6f);
        vwrite(1, y, sc);
        eig = e1v;
        __syncthreads();
    }
    // ---- peeled iteration 2 (synchronous): u_2 = y_2/e_2, n_2 = 1 ----
    if (niter >= 2) {
        matvec2(afr, vsel + 512, h, y);
        npart(0, y);
        __syncthreads();
        float e2v = sqrtf(psum(0));
        float sc  = __builtin_amdgcn_rcpf(e2v + 1e-6f);
        vwrite(0, y, sc);
        eig = e2v;
        sc_m1 = sc;   // s_2
        nm2   = 1.0f; // n_1
        __syncthreads();
    }

    // ---- pipelined iterations 3..niter: one barrier each ----
    int wr = 0;
    for (int t = 3; t <= niter; ++t) {
        const int rd = wr;    // buffer holding u_{t-1}, part[rd] = q_{t-1}
        wr ^= 1;
        float q   = psum(rd);                                  // ||y_{t-1}||^2
        float e1v = __builtin_amdgcn_sqrtf(q);                 // e_{t-1}
        float nm1 = e1v * sc_m1;                               // n_{t-1}
        float sc  = nm2 * __builtin_amdgcn_rcpf(e1v * nm1 + 1e-12f);  // s_t
        matvec2(afr, vsel + (size_t)rd * 512, h, y);           // y_t
        vwrite(wr, y, sc);
        npart(wr, y);
        nm2 = nm1; sc_m1 = sc;
        __syncthreads();
    }

    // ---- epilogue: exact eig = ||y_T|| / n_{T-1}
    if (niter >= 3) {
        float qT = psum(wr);
        eig = sqrtf(qT) / (nm2 + 1e-12f);
    }
    if (tid == 0) out[b] = eig;
}

extern "C" void kernel_launch(void* const* d_in, const int* in_sizes, int n_in,
                              void* d_out, int out_size, void* d_ws, size_t ws_size,
                              hipStream_t stream) {
    const float* Are = (const float*)d_in[0];
    const float* Aim = (const float*)d_in[1];
    const float* vre = (const float*)d_in[2];
    const float* vim = (const float*)d_in[3];
    const int* niter = (const int*)d_in[4];
    float* out = (float*)d_out;

    f16* AhAre = (f16*)d_ws;                                            // 32 MB
    f16* AhAim = (f16*)((char*)d_ws + (size_t)32 * 1024 * 1024);        // 32 MB

    k_gemm<<<dim3(256), dim3(1024), 0, stream>>>(Are, Aim, AhAre, AhAim);
    k_power<<<dim3(256), dim3(512), 0, stream>>>(AhAre, AhAim, vre, vim, niter, out);
}

// Round 14
// 117.041 us; speedup vs baseline: 1.0719x; 1.0719x over previous
//
#include <hip/hip_runtime.h>
#include <cstdint>

typedef _Float16 f16;
typedef _Float16 f16x8 __attribute__((ext_vector_type(8)));
typedef float    f32x4 __attribute__((ext_vector_type(4)));

static __device__ __forceinline__ uint32_t pack2(float x, float y) {
    f16 hx = (f16)x, hy = (f16)y;
    uint32_t ux = __builtin_bit_cast(unsigned short, hx);
    uint32_t uy = __builtin_bit_cast(unsigned short, hy);
    return ux | (uy << 16);
}

// ---------------------------------------------------------------------------
// Kernel 1 (fused transpose+gemm, THREE QUADRANT BLOCKS PER BATCH):
// Evidence r7/r11/r12: one 8-wave block/CU is schedule-invariant at ~73us
// (MfmaUtil 13%, 2.4TB/s, Occ 19%) -- phase-locked waves, nothing overlaps.
// r13: 16-wave monolithic block spills (acc 512KB/batch = whole CU RF).
// Fix: split output into 3 Hermitian quadrant-blocks per batch, each
// 512 thr with acc=64 regs (total ~100): __launch_bounds__(512,4) -> TWO
// blocks co-resident per CU (16 waves), m114-style cross-block overlap.
//   qq=0: rows 0..127 x cols 0..127      (stage lo n-half,  32KB LDS)
//   qq=1: rows 0..127 x cols 128..255    (stage both halves) + mirror q2
//   qq=2: rows 128..255 x cols 128..255  (stage hi n-half)
// Single-buffer serial staging (2 barriers/step) -- TLP does the hiding.
// Staging map/swizzle = r11-pass1 verified formulas; per-output MFMA
// K-order identical to r7/r12 -> absmax preserved.  Grid 768, XCD swizzle.
// ---------------------------------------------------------------------------
__global__ __launch_bounds__(512, 4) void k_gemm(const float* __restrict__ Are,
                                                 const float* __restrict__ Aim,
                                                 f16* __restrict__ AhAre,
                                                 f16* __restrict__ AhAim) {
    const int tid = threadIdx.x;
    int bid0 = blockIdx.x;
    int bid = (bid0 & 7) * 96 + (bid0 >> 3);     // bijective: 768 % 8 == 0
    const int b  = bid / 3;
    const int qq = bid - 3 * b;
    const int R0 = (qq == 2) ? 128 : 0;
    const int C0 = (qq == 0) ? 0 : 128;
    const int nb0 = (qq == 2) ? 128 : 0;         // global n-base of staged half 1
    const int boff = (qq == 1) ? 128 : 0;        // local n-base of B-operand

    __shared__ __align__(16) f16 ls[2][256 * 32];   // [plane][n_local*32+m'] 32KB

    const int l = tid & 63, g = tid >> 6;        // lane, wave 0..7
    const int lr = l & 15, lk = l >> 4;
    const int u = tid & 15, fp = tid >> 4;       // m-pair 0..15, n-quad 0..31
    const int su = u >> 2, uq = u & 3;

    f16* oR = AhAre + (size_t)b * 65536;
    f16* oI = AhAim + (size_t)b * 65536;

    f32x4 cR[8], cI[8];
#pragma unroll
    for (int j = 0; j < 8; ++j) { cR[j] = (f32x4)0.0f; cI[j] = (f32x4)0.0f; }

    for (int m0 = 0; m0 < 256; m0 += 32) {
        __syncthreads();
        // ---- stage half 1: global n in [nb0, nb0+128) -> local [0,128)
#pragma unroll
        for (int t = 0; t < 2; ++t) {
            const float* sp = (t ? Aim : Are) + (size_t)b * 65536
                            + (size_t)(m0 + 2 * u) * 256 + nb0 + fp * 4;
            float4 x = *(const float4*)(sp);
            float4 y = *(const float4*)(sp + 256);
            float xv[4] = {x.x, x.y, x.z, x.w};
            float yv[4] = {y.x, y.y, y.z, y.w};
            uint32_t* lw = (uint32_t*)&ls[t][0];
#pragma unroll
            for (int i = 0; i < 4; ++i) {
                int r = fp * 4 + i;
                int s = su ^ ((r >> 1) & 3);
                lw[r * 16 + s * 4 + uq] = pack2(xv[i], yv[i]);
            }
        }
        // ---- qq==1 also stages hi half: global n 128.. -> local 128..
        if (qq == 1) {
#pragma unroll
            for (int t = 0; t < 2; ++t) {
                const float* sp = (t ? Aim : Are) + (size_t)b * 65536
                                + (size_t)(m0 + 2 * u) * 256 + 128 + fp * 4;
                float4 x = *(const float4*)(sp);
                float4 y = *(const float4*)(sp + 256);
                float xv[4] = {x.x, x.y, x.z, x.w};
                float yv[4] = {y.x, y.y, y.z, y.w};
                uint32_t* lw = (uint32_t*)&ls[t][0];
#pragma unroll
                for (int i = 0; i < 4; ++i) {
                    int r = 128 + fp * 4 + i;
                    int s = su ^ ((r >> 1) & 3);
                    lw[r * 16 + s * 4 + uq] = pack2(xv[i], yv[i]);
                }
            }
        }
        __syncthreads();

        // ---- A fragment: local row 16g+lr
        const int ra = 16 * g + lr;
        const int sa = lk ^ ((ra >> 1) & 3);
        f16x8 a1re = *(const f16x8*)(&ls[0][ra * 32 + sa * 8]);
        uint4 u1   = *(const uint4*)(&ls[1][ra * 32 + sa * 8]);
        f16x8 a1im = __builtin_bit_cast(f16x8, u1);
        uint4 n1 = make_uint4(u1.x ^ 0x80008000u, u1.y ^ 0x80008000u,
                              u1.z ^ 0x80008000u, u1.w ^ 0x80008000u);
        f16x8 na1 = __builtin_bit_cast(f16x8, n1);

#pragma unroll
        for (int j = 0; j < 8; ++j) {
            int rb = boff + 16 * j + lr;
            int sb = lk ^ ((rb >> 1) & 3);
            f16x8 bre = *(const f16x8*)(&ls[0][rb * 32 + sb * 8]);
            f16x8 bim = *(const f16x8*)(&ls[1][rb * 32 + sb * 8]);
            cR[j] = __builtin_amdgcn_mfma_f32_16x16x32_f16(a1re, bre, cR[j], 0, 0, 0);
            cR[j] = __builtin_amdgcn_mfma_f32_16x16x32_f16(a1im, bim, cR[j], 0, 0, 0);
            cI[j] = __builtin_amdgcn_mfma_f32_16x16x32_f16(a1re, bim, cI[j], 0, 0, 0);
            cI[j] = __builtin_amdgcn_mfma_f32_16x16x32_f16(na1,  bre, cI[j], 0, 0, 0);
        }
    }

    // ---- epilogue: direct store of this quadrant
#pragma unroll
    for (int j = 0; j < 8; ++j)
#pragma unroll
        for (int r = 0; r < 4; ++r) {
            int n = R0 + 16 * g + lk * 4 + r;
            int c = C0 + 16 * j + lr;
            oR[(size_t)n * 256 + c] = (f16)cR[j][r];
            oI[(size_t)n * 256 + c] = (f16)cI[j][r];
        }

    // ---- Hermitian mirror (qq==1): q2[128+jj][nn] = conj(q1[nn][128+jj])
    if (qq == 1) {
        f16* lsm = &ls[0][0];                    // reuse 32KB as [128][128]
        const int jjo = tid >> 2, qtr = tid & 3;

        __syncthreads();                         // all ls frag-reads done
        // Re plane: copy
#pragma unroll
        for (int j = 0; j < 8; ++j)
#pragma unroll
            for (int r = 0; r < 4; ++r) {
                int jj = 16 * j + lr;            // col - 128
                int nn = 16 * g + lk * 4 + r;
                lsm[jj * 128 + nn] = (f16)cR[j][r];
            }
        __syncthreads();
        {
            const f16* srow = lsm + jjo * 128 + qtr * 32;
            f16* drow = oR + (size_t)(128 + jjo) * 256 + qtr * 32;
#pragma unroll
            for (int ch = 0; ch < 4; ++ch)
                *(uint4*)(void*)(drow + ch * 8) = *(const uint4*)(srow + ch * 8);
        }
        __syncthreads();
        // Im plane: negate
#pragma unroll
        for (int j = 0; j < 8; ++j)
#pragma unroll
            for (int r = 0; r < 4; ++r) {
                int jj = 16 * j + lr;
                int nn = 16 * g + lk * 4 + r;
                lsm[jj * 128 + nn] = (f16)(-cI[j][r]);
            }
        __syncthreads();
        {
            const f16* srow = lsm + jjo * 128 + qtr * 32;
            f16* drow = oI + (size_t)(128 + jjo) * 256 + qtr * 32;
#pragma unroll
            for (int ch = 0; ch < 4; ++ch)
                *(uint4*)(void*)(drow + ch * 8) = *(const uint4*)(srow + ch * 8);
        }
    }
}

// ---------------------------------------------------------------------------
// Kernel 2: power iteration, 8-WAVE / 32-ROWS-PER-WAVE form (unchanged:
// ~26us).  Deferred normalization (stable form).
// ---------------------------------------------------------------------------
static __device__ __forceinline__ void matvec2(const f16x8 (&afr)[2][16],
                                               const f16* __restrict__ vs, int h,
                                               float4 (&y)[2]) {
    f16x8 bf[16];
#pragma unroll
    for (int c = 0; c < 16; ++c) bf[c] = *(const f16x8*)(vs + 32 * c + 8 * h);
    f32x4 P0[2], P1[2];
#pragma unroll
    for (int rg = 0; rg < 2; ++rg) { P0[rg] = (f32x4)0.0f; P1[rg] = (f32x4)0.0f; }
#pragma unroll
    for (int c = 0; c < 16; ++c) {
#pragma unroll
        for (int rg = 0; rg < 2; ++rg) {
            if (c & 1) P1[rg] = __builtin_amdgcn_mfma_f32_16x16x32_f16(afr[rg][c], bf[c], P1[rg], 0, 0, 0);
            else       P0[rg] = __builtin_amdgcn_mfma_f32_16x16x32_f16(afr[rg][c], bf[c], P0[rg], 0, 0, 0);
        }
    }
#pragma unroll
    for (int rg = 0; rg < 2; ++rg)
        y[rg] = make_float4(P0[rg][0] + P1[rg][0], P0[rg][1] + P1[rg][1],
                            P0[rg][2] + P1[rg][2], P0[rg][3] + P1[rg][3]);
}

__global__ __launch_bounds__(512, 2) void k_power(const f16* __restrict__ AhAre,
                                                  const f16* __restrict__ AhAim,
                                                  const float* __restrict__ vre,
                                                  const float* __restrict__ vim,
                                                  const int* __restrict__ pniter,
                                                  float* __restrict__ out) {
    const int tid = threadIdx.x;
    const int b = blockIdx.x;
    const int l = tid & 63;            // lane
    const int g = tid >> 6;            // wave 0..7
    const int sel = l & 15;            // A-row-within-group / B-col
    const int h = l >> 4;              // k-slot 0..3

    __shared__ __align__(16) f16 v0h[2][512];   // [buf][ vr ; -vi ]
    __shared__ __align__(16) f16 v1h[2][512];   // [buf][ vi ;  vr ]
    __shared__ __align__(16) float part[2][8];

    // ---- load A fragments: wave g owns rows 32g .. 32g+31 (2 row-groups)
    f16x8 afr[2][16];
#pragma unroll
    for (int rg = 0; rg < 2; ++rg) {
        const int m = 32 * g + 16 * rg + sel;
        const f16* bR = AhAre + (size_t)b * 65536 + (size_t)m * 256 + 8 * h;
        const f16* bI = AhAim + (size_t)b * 65536 + (size_t)m * 256 + 8 * h;
#pragma unroll
        for (int c = 0; c < 8; ++c) {
            afr[rg][c]     = *(const f16x8*)(bR + 32 * c);
            afr[rg][8 + c] = *(const f16x8*)(bI + 32 * c);
        }
    }
#pragma unroll
    for (int rg = 0; rg < 2; ++rg)
#pragma unroll
        for (int c = 0; c < 16; ++c) asm volatile("" : "+a"(afr[rg][c]));

    if (tid < 256) {
        float xr = vre[b * 256 + tid], xi = vim[b * 256 + tid];
        v0h[0][tid]       = (f16)xr;
        v0h[0][256 + tid] = (f16)(-xi);
        v1h[0][tid]       = (f16)xi;
        v1h[0][256 + tid] = (f16)xr;
    }
    __syncthreads();

    const int niter = *pniter;
    const f16* vsel = (sel == 0) ? &v0h[0][0] : &v1h[0][0];

    float eig = 0.0f;

    auto npart = [&](int wb, const float4 (&y)[2]) {
        float s_ = 0.0f;
        if (sel < 2) {
#pragma unroll
            for (int rg = 0; rg < 2; ++rg)
                s_ += y[rg].x * y[rg].x + y[rg].y * y[rg].y
                    + y[rg].z * y[rg].z + y[rg].w * y[rg].w;
        }
        s_ += __shfl_xor(s_, 1, 64);
        s_ += __shfl_xor(s_, 16, 64);
        s_ += __shfl_xor(s_, 32, 64);
        if (l == 0) part[wb][g] = s_;
    };
    auto vwrite = [&](int wb, const float4 (&y)[2], float sc) {
        if (sel < 2) {
#pragma unroll
            for (int rg = 0; rg < 2; ++rg) {
                uint32_t w0 = pack2(y[rg].x * sc, y[rg].y * sc);
                uint32_t w1 = pack2(y[rg].z * sc, y[rg].w * sc);
                int m0 = 32 * g + 16 * rg + 4 * h;    // 4 consecutive rows
                if (sel == 0) {                       // y = new vr
                    *(uint2*)(void*)(&v0h[wb][m0])       = make_uint2(w0, w1);
                    *(uint2*)(void*)(&v1h[wb][256 + m0]) = make_uint2(w0, w1);
                } else {                              // y = new vi
                    *(uint2*)(void*)(&v1h[wb][m0])       = make_uint2(w0, w1);
                    *(uint2*)(void*)(&v0h[wb][256 + m0]) =
                        make_uint2(w0 ^ 0x80008000u, w1 ^ 0x80008000u);
                }
            }
        }
    };
    auto psum = [&](int rb) -> float {
        float4 q0 = *(const float4*)(&part[rb][0]);
        float4 q1 = *(const float4*)(&part[rb][4]);
        return (q0.x + q0.y + q0.z + q0.w) + (q1.x + q1.y + q1.z + q1.w);
    };

    float sc_m1 = 1.0f;   // s_{t-1}
    float nm2   = 1.0f;   // n_{t-2}

    float4 y[2];

    // ---- peeled iteration 1 (synchronous): u_1 = y_1/e_1, n_1 = 1 ----
    if (niter >= 1) {
        matvec2(afr, vsel, h, y);
        npart(1, y);
        __syncthreads();
        float e1v = sqrtf(psum(1));
        float sc  = __builtin_amdgcn_rcpf(e1v + 1e-6f);
        vwrite(1, y, sc);
        eig = e1v;
        __syncthreads();
    }
    // ---- peeled iteration 2 (synchronous): u_2 = y_2/e_2, n_2 = 1 ----
    if (niter >= 2) {
        matvec2(afr, vsel + 512, h, y);
        npart(0, y);
        __syncthreads();
        float e2v = sqrtf(psum(0));
        float sc  = __builtin_amdgcn_rcpf(e2v + 1e-6f);
        vwrite(0, y, sc);
        eig = e2v;
        sc_m1 = sc;   // s_2
        nm2   = 1.0f; // n_1
        __syncthreads();
    }

    // ---- pipelined iterations 3..niter: one barrier each ----
    int wr = 0;
    for (int t = 3; t <= niter; ++t) {
        const int rd = wr;    // buffer holding u_{t-1}, part[rd] = q_{t-1}
        wr ^= 1;
        float q   = psum(rd);                                  // ||y_{t-1}||^2
        float e1v = __builtin_amdgcn_sqrtf(q);                 // e_{t-1}
        float nm1 = e1v * sc_m1;                               // n_{t-1}
        float sc  = nm2 * __builtin_amdgcn_rcpf(e1v * nm1 + 1e-12f);  // s_t
        matvec2(afr, vsel + (size_t)rd * 512, h, y);           // y_t
        vwrite(wr, y, sc);
        npart(wr, y);
        nm2 = nm1; sc_m1 = sc;
        __syncthreads();
    }

    // ---- epilogue: exact eig = ||y_T|| / n_{T-1}
    if (niter >= 3) {
        float qT = psum(wr);
        eig = sqrtf(qT) / (nm2 + 1e-12f);
    }
    if (tid == 0) out[b] = eig;
}

extern "C" void kernel_launch(void* const* d_in, const int* in_sizes, int n_in,
                              void* d_out, int out_size, void* d_ws, size_t ws_size,
                              hipStream_t stream) {
    const float* Are = (const float*)d_in[0];
    const float* Aim = (const float*)d_in[1];
    const float* vre = (const float*)d_in[2];
    const float* vim = (const float*)d_in[3];
    const int* niter = (const int*)d_in[4];
    float* out = (float*)d_out;

    f16* AhAre = (f16*)d_ws;                                            // 32 MB
    f16* AhAim = (f16*)((char*)d_ws + (size_t)32 * 1024 * 1024);        // 32 MB

    k_gemm<<<dim3(768), dim3(512), 0, stream>>>(Are, Aim, AhAre, AhAim);
    k_power<<<dim3(256), dim3(512), 0, stream>>>(AhAre, AhAim, vre, vim, niter, out);
}

// Round 15
// 107.144 us; speedup vs baseline: 1.1709x; 1.0924x over previous
//
#include <hip/hip_runtime.h>
#include <cstdint>

typedef _Float16 f16;
typedef _Float16 f16x8 __attribute__((ext_vector_type(8)));
typedef float    f32x4 __attribute__((ext_vector_type(4)));

static __device__ __forceinline__ uint32_t pack2(float x, float y) {
    f16 hx = (f16)x, hy = (f16)y;
    uint32_t ux = __builtin_bit_cast(unsigned short, hx);
    uint32_t uy = __builtin_bit_cast(unsigned short, hy);
    return ux | (uy << 16);
}

// Clean barrier: drain LDS ops only (no "memory" clobber -> no vmcnt drain).
static __device__ __forceinline__ void lds_barrier() {
    __builtin_amdgcn_sched_barrier(0);
    asm volatile("s_waitcnt lgkmcnt(0)");
    __builtin_amdgcn_s_barrier();
    __builtin_amdgcn_sched_barrier(0);
}

// ---------------------------------------------------------------------------
// Kernel 1 (fused transpose+gemm, one block/batch, TWO-PASS, BK=64):
// r7-r14 evidence: gemm is invariant (~71-85us, 2.2-2.5 TB/s) across serial/
// pipelined/occupancy variants -- all shared BK=32's 16 fine-grained phases.
// Surviving hypothesis: per-phase fixed cost (burst ramp + barrier + exposed
// tail latency).  This round: BK=64 -> HALF the phases, 2x the burst/phase.
//   pass 0: rows 0..127  x cols 0..255, 4 K-steps (128 acc regs)
//           + store + Hermitian mirror of q2
//   pass 1: rows 128..255 x cols 128..255, 4 K-steps (64 acc regs)
// Single 64KB LDS buffer [2 planes][256n][64m], 2 lds_barriers/step; next
// step's loads (64 transient regs) issue between bar1 and MFMA.  Swizzle
// per 32-m sub-block = verified r11 map; sub-outer MFMA loop keeps per-
// output K-order bitwise identical to r11 -> absmax preserved.
// Reg peak ~236 <= r7's proven-clean ~252 (512-thr block cap 256).
// ---------------------------------------------------------------------------
__global__ __launch_bounds__(512, 2) void k_gemm(const float* __restrict__ Are,
                                                 const float* __restrict__ Aim,
                                                 f16* __restrict__ AhAre,
                                                 f16* __restrict__ AhAim) {
    const int tid = threadIdx.x;
    const int b = blockIdx.x;

    __shared__ __align__(16) f16 ls[2][256 * 64];   // [plane][n*64+m'] 64KB

    const int l = tid & 63, g = tid >> 6;      // lane, wave 0..7
    const int lr = l & 15, lk = l >> 4;
    const int u = tid & 15, fp = tid >> 4;     // m-pair-in-sub, n-group
    const int su = u >> 2, uq = u & 3;

    f16* oR = AhAre + (size_t)b * 65536;
    f16* oI = AhAim + (size_t)b * 65536;

    // ======================= PASS 0: rows 0..127, full width ================
    {
        f32x4 cR[16], cI[16];
#pragma unroll
        for (int j = 0; j < 16; ++j) { cR[j] = (f32x4)0.0f; cI[j] = (f32x4)0.0f; }

        // v[plane][sub][quad]: 16 float4 (64 regs, dead during pack/MFMA tail)
        float4 v[2][2][4];
        auto load0 = [&](int m0) {
#pragma unroll
            for (int t = 0; t < 2; ++t)
#pragma unroll
                for (int sub = 0; sub < 2; ++sub) {
                    const float* sp = (t ? Aim : Are) + (size_t)b * 65536
                                    + (size_t)(m0 + 32 * sub + 2 * u) * 256 + fp * 8;
                    v[t][sub][0] = *(const float4*)(sp);
                    v[t][sub][1] = *(const float4*)(sp + 4);
                    v[t][sub][2] = *(const float4*)(sp + 256);
                    v[t][sub][3] = *(const float4*)(sp + 260);
                }
        };

        load0(0);   // prologue

#pragma unroll
        for (int step = 0; step < 4; ++step) {
            // ---- pack current tile -> LDS (row stride 64 f16 = 32 u32)
#pragma unroll
            for (int t = 0; t < 2; ++t)
#pragma unroll
                for (int sub = 0; sub < 2; ++sub) {
                    float xv[8] = {v[t][sub][0].x, v[t][sub][0].y, v[t][sub][0].z, v[t][sub][0].w,
                                   v[t][sub][1].x, v[t][sub][1].y, v[t][sub][1].z, v[t][sub][1].w};
                    float yv[8] = {v[t][sub][2].x, v[t][sub][2].y, v[t][sub][2].z, v[t][sub][2].w,
                                   v[t][sub][3].x, v[t][sub][3].y, v[t][sub][3].z, v[t][sub][3].w};
                    uint32_t* lw = (uint32_t*)&ls[t][0];
#pragma unroll
                    for (int i = 0; i < 8; ++i) {
                        int r = fp * 8 + i;
                        int s = su ^ ((r >> 1) & 3);
                        lw[r * 32 + sub * 16 + s * 4 + uq] = pack2(xv[i], yv[i]);
                    }
                }

            lds_barrier();                      // bar1: writes visible

            // next step's loads: issue now, land during MFMA (reg dest)
            if (step < 3) load0(64 * (step + 1));
            __builtin_amdgcn_sched_barrier(0);  // pin loads before MFMA

            // ---- MFMA from LDS: sub-outer keeps K-order = r11 (bitwise)
#pragma unroll
            for (int sub = 0; sub < 2; ++sub) {
                const int ra = 16 * g + lr;             // 0..127
                const int sa = lk ^ ((ra >> 1) & 3);
                f16x8 are = *(const f16x8*)(&ls[0][ra * 64 + sub * 32 + sa * 8]);
                uint4 u1  = *(const uint4*)(&ls[1][ra * 64 + sub * 32 + sa * 8]);
                f16x8 aim = __builtin_bit_cast(f16x8, u1);
                uint4 n1 = make_uint4(u1.x ^ 0x80008000u, u1.y ^ 0x80008000u,
                                      u1.z ^ 0x80008000u, u1.w ^ 0x80008000u);
                f16x8 nai = __builtin_bit_cast(f16x8, n1);
#pragma unroll
                for (int j = 0; j < 16; ++j) {
                    int rb = 16 * j + lr;
                    int sb = lk ^ ((rb >> 1) & 3);
                    f16x8 bre = *(const f16x8*)(&ls[0][rb * 64 + sub * 32 + sb * 8]);
                    f16x8 bim = *(const f16x8*)(&ls[1][rb * 64 + sub * 32 + sb * 8]);
                    cR[j] = __builtin_amdgcn_mfma_f32_16x16x32_f16(are, bre, cR[j], 0, 0, 0);
                    cR[j] = __builtin_amdgcn_mfma_f32_16x16x32_f16(aim, bim, cR[j], 0, 0, 0);
                    cI[j] = __builtin_amdgcn_mfma_f32_16x16x32_f16(are, bim, cI[j], 0, 0, 0);
                    cI[j] = __builtin_amdgcn_mfma_f32_16x16x32_f16(nai, bre, cI[j], 0, 0, 0);
                }
            }

            lds_barrier();                      // bar2: reads done pre-overwrite
        }

        // ---- pass-0 epilogue: direct store rows 16g (all cols)
#pragma unroll
        for (int j = 0; j < 16; ++j)
#pragma unroll
            for (int r = 0; r < 4; ++r) {
                int n = 16 * g + lk * 4 + r;
                int c = 16 * j + lr;
                oR[(size_t)n * 256 + c] = (f16)cR[j][r];
                oI[(size_t)n * 256 + c] = (f16)cI[j][r];
            }

        // ---- Hermitian mirror: q2[128+jj][nn] = conj(q1[nn][128+jj])
        f16* lsm = &ls[0][0];                   // reuse 32KB as [128][128]
        const int jj_out = tid >> 2, qtr = tid & 3;

        __syncthreads();
        // Re plane: copy
#pragma unroll
        for (int j = 8; j < 16; ++j)
#pragma unroll
            for (int r = 0; r < 4; ++r) {
                int jj = 16 * (j - 8) + lr;
                int nn = 16 * g + lk * 4 + r;
                lsm[jj * 128 + nn] = (f16)cR[j][r];
            }
        __syncthreads();
        {
            const f16* srow = lsm + jj_out * 128 + qtr * 32;
            f16* drow = oR + (size_t)(128 + jj_out) * 256 + qtr * 32;
#pragma unroll
            for (int ch = 0; ch < 4; ++ch)
                *(uint4*)(void*)(drow + ch * 8) = *(const uint4*)(srow + ch * 8);
        }
        __syncthreads();
        // Im plane: negate
#pragma unroll
        for (int j = 8; j < 16; ++j)
#pragma unroll
            for (int r = 0; r < 4; ++r) {
                int jj = 16 * (j - 8) + lr;
                int nn = 16 * g + lk * 4 + r;
                lsm[jj * 128 + nn] = (f16)(-cI[j][r]);
            }
        __syncthreads();
        {
            const f16* srow = lsm + jj_out * 128 + qtr * 32;
            f16* drow = oI + (size_t)(128 + jj_out) * 256 + qtr * 32;
#pragma unroll
            for (int ch = 0; ch < 4; ++ch)
                *(uint4*)(void*)(drow + ch * 8) = *(const uint4*)(srow + ch * 8);
        }
        __syncthreads();                        // protect ls for pass 1
    }

    // =============== PASS 1: rows 128..255, cols 128..255 ===================
    {
        f32x4 dR[8], dI[8];
#pragma unroll
        for (int j = 0; j < 8; ++j) { dR[j] = (f32x4)0.0f; dI[j] = (f32x4)0.0f; }

        // 128 local n-rows: fp covers n in groups of 4; 8 float4/thread
        float4 w[2][2][2];   // [plane][sub][row]
        auto load1 = [&](int m0) {
#pragma unroll
            for (int t = 0; t < 2; ++t)
#pragma unroll
                for (int sub = 0; sub < 2; ++sub) {
                    const float* sp = (t ? Aim : Are) + (size_t)b * 65536
                                    + (size_t)(m0 + 32 * sub + 2 * u) * 256 + 128 + fp * 4;
                    w[t][sub][0] = *(const float4*)(sp);
                    w[t][sub][1] = *(const float4*)(sp + 256);
                }
        };

        load1(0);

#pragma unroll
        for (int step = 0; step < 4; ++step) {
#pragma unroll
            for (int t = 0; t < 2; ++t)
#pragma unroll
                for (int sub = 0; sub < 2; ++sub) {
                    float xv[4] = {w[t][sub][0].x, w[t][sub][0].y, w[t][sub][0].z, w[t][sub][0].w};
                    float yv[4] = {w[t][sub][1].x, w[t][sub][1].y, w[t][sub][1].z, w[t][sub][1].w};
                    uint32_t* lw = (uint32_t*)&ls[t][0];
#pragma unroll
                    for (int i = 0; i < 4; ++i) {
                        int r = fp * 4 + i;                 // local n (0..127)
                        int s = su ^ ((r >> 1) & 3);
                        lw[r * 32 + sub * 16 + s * 4 + uq] = pack2(xv[i], yv[i]);
                    }
                }

            lds_barrier();

            if (step < 3) load1(64 * (step + 1));
            __builtin_amdgcn_sched_barrier(0);

#pragma unroll
            for (int sub = 0; sub < 2; ++sub) {
                const int ra = 16 * g + lr;                 // local (gl-128)
                const int sa = lk ^ ((ra >> 1) & 3);
                f16x8 are = *(const f16x8*)(&ls[0][ra * 64 + sub * 32 + sa * 8]);
                uint4 u2  = *(const uint4*)(&ls[1][ra * 64 + sub * 32 + sa * 8]);
                f16x8 aim = __builtin_bit_cast(f16x8, u2);
                uint4 n2 = make_uint4(u2.x ^ 0x80008000u, u2.y ^ 0x80008000u,
                                      u2.z ^ 0x80008000u, u2.w ^ 0x80008000u);
                f16x8 nai = __builtin_bit_cast(f16x8, n2);
#pragma unroll
                for (int j = 0; j < 8; ++j) {
                    int rb = 16 * j + lr;                   // local col
                    int sb = lk ^ ((rb >> 1) & 3);
                    f16x8 bre = *(const f16x8*)(&ls[0][rb * 64 + sub * 32 + sb * 8]);
                    f16x8 bim = *(const f16x8*)(&ls[1][rb * 64 + sub * 32 + sb * 8]);
                    dR[j] = __builtin_amdgcn_mfma_f32_16x16x32_f16(are, bre, dR[j], 0, 0, 0);
                    dR[j] = __builtin_amdgcn_mfma_f32_16x16x32_f16(aim, bim, dR[j], 0, 0, 0);
                    dI[j] = __builtin_amdgcn_mfma_f32_16x16x32_f16(are, bim, dI[j], 0, 0, 0);
                    dI[j] = __builtin_amdgcn_mfma_f32_16x16x32_f16(nai, bre, dI[j], 0, 0, 0);
                }
            }

            lds_barrier();
        }

        // pass-1 epilogue: rows 128+16g, cols 128..255
#pragma unroll
        for (int j = 0; j < 8; ++j)
#pragma unroll
            for (int r = 0; r < 4; ++r) {
                int n = 128 + 16 * g + lk * 4 + r;
                int c = 128 + 16 * j + lr;
                oR[(size_t)n * 256 + c] = (f16)dR[j][r];
                oI[(size_t)n * 256 + c] = (f16)dI[j][r];
            }
    }
}

// ---------------------------------------------------------------------------
// Kernel 2: power iteration, 8-WAVE / 32-ROWS-PER-WAVE form (unchanged:
// ~26us).  Deferred normalization (stable form).
// ---------------------------------------------------------------------------
static __device__ __forceinline__ void matvec2(const f16x8 (&afr)[2][16],
                                               const f16* __restrict__ vs, int h,
                                               float4 (&y)[2]) {
    f16x8 bf[16];
#pragma unroll
    for (int c = 0; c < 16; ++c) bf[c] = *(const f16x8*)(vs + 32 * c + 8 * h);
    f32x4 P0[2], P1[2];
#pragma unroll
    for (int rg = 0; rg < 2; ++rg) { P0[rg] = (f32x4)0.0f; P1[rg] = (f32x4)0.0f; }
#pragma unroll
    for (int c = 0; c < 16; ++c) {
#pragma unroll
        for (int rg = 0; rg < 2; ++rg) {
            if (c & 1) P1[rg] = __builtin_amdgcn_mfma_f32_16x16x32_f16(afr[rg][c], bf[c], P1[rg], 0, 0, 0);
            else       P0[rg] = __builtin_amdgcn_mfma_f32_16x16x32_f16(afr[rg][c], bf[c], P0[rg], 0, 0, 0);
        }
    }
#pragma unroll
    for (int rg = 0; rg < 2; ++rg)
        y[rg] = make_float4(P0[rg][0] + P1[rg][0], P0[rg][1] + P1[rg][1],
                            P0[rg][2] + P1[rg][2], P0[rg][3] + P1[rg][3]);
}

__global__ __launch_bounds__(512, 2) void k_power(const f16* __restrict__ AhAre,
                                                  const f16* __restrict__ AhAim,
                                                  const float* __restrict__ vre,
                                                  const float* __restrict__ vim,
                                                  const int* __restrict__ pniter,
                                                  float* __restrict__ out) {
    const int tid = threadIdx.x;
    const int b = blockIdx.x;
    const int l = tid & 63;            // lane
    const int g = tid >> 6;            // wave 0..7
    const int sel = l & 15;            // A-row-within-group / B-col
    const int h = l >> 4;              // k-slot 0..3

    __shared__ __align__(16) f16 v0h[2][512];   // [buf][ vr ; -vi ]
    __shared__ __align__(16) f16 v1h[2][512];   // [buf][ vi ;  vr ]
    __shared__ __align__(16) float part[2][8];

    // ---- load A fragments: wave g owns rows 32g .. 32g+31 (2 row-groups)
    f16x8 afr[2][16];
#pragma unroll
    for (int rg = 0; rg < 2; ++rg) {
        const int m = 32 * g + 16 * rg + sel;
        const f16* bR = AhAre + (size_t)b * 65536 + (size_t)m * 256 + 8 * h;
        const f16* bI = AhAim + (size_t)b * 65536 + (size_t)m * 256 + 8 * h;
#pragma unroll
        for (int c = 0; c < 8; ++c) {
            afr[rg][c]     = *(const f16x8*)(bR + 32 * c);
            afr[rg][8 + c] = *(const f16x8*)(bI + 32 * c);
        }
    }
#pragma unroll
    for (int rg = 0; rg < 2; ++rg)
#pragma unroll
        for (int c = 0; c < 16; ++c) asm volatile("" : "+a"(afr[rg][c]));

    if (tid < 256) {
        float xr = vre[b * 256 + tid], xi = vim[b * 256 + tid];
        v0h[0][tid]       = (f16)xr;
        v0h[0][256 + tid] = (f16)(-xi);
        v1h[0][tid]       = (f16)xi;
        v1h[0][256 + tid] = (f16)xr;
    }
    __syncthreads();

    const int niter = *pniter;
    const f16* vsel = (sel == 0) ? &v0h[0][0] : &v1h[0][0];

    float eig = 0.0f;

    auto npart = [&](int wb, const float4 (&y)[2]) {
        float s_ = 0.0f;
        if (sel < 2) {
#pragma unroll
            for (int rg = 0; rg < 2; ++rg)
                s_ += y[rg].x * y[rg].x + y[rg].y * y[rg].y
                    + y[rg].z * y[rg].z + y[rg].w * y[rg].w;
        }
        s_ += __shfl_xor(s_, 1, 64);
        s_ += __shfl_xor(s_, 16, 64);
        s_ += __shfl_xor(s_, 32, 64);
        if (l == 0) part[wb][g] = s_;
    };
    auto vwrite = [&](int wb, const float4 (&y)[2], float sc) {
        if (sel < 2) {
#pragma unroll
            for (int rg = 0; rg < 2; ++rg) {
                uint32_t w0 = pack2(y[rg].x * sc, y[rg].y * sc);
                uint32_t w1 = pack2(y[rg].z * sc, y[rg].w * sc);
                int m0 = 32 * g + 16 * rg + 4 * h;    // 4 consecutive rows
                if (sel == 0) {                       // y = new vr
                    *(uint2*)(void*)(&v0h[wb][m0])       = make_uint2(w0, w1);
                    *(uint2*)(void*)(&v1h[wb][256 + m0]) = make_uint2(w0, w1);
                } else {                              // y = new vi
                    *(uint2*)(void*)(&v1h[wb][m0])       = make_uint2(w0, w1);
                    *(uint2*)(void*)(&v0h[wb][256 + m0]) =
                        make_uint2(w0 ^ 0x80008000u, w1 ^ 0x80008000u);
                }
            }
        }
    };
    auto psum = [&](int rb) -> float {
        float4 q0 = *(const float4*)(&part[rb][0]);
        float4 q1 = *(const float4*)(&part[rb][4]);
        return (q0.x + q0.y + q0.z + q0.w) + (q1.x + q1.y + q1.z + q1.w);
    };

    float sc_m1 = 1.0f;   // s_{t-1}
    float nm2   = 1.0f;   // n_{t-2}

    float4 y[2];

    // ---- peeled iteration 1 (synchronous): u_1 = y_1/e_1, n_1 = 1 ----
    if (niter >= 1) {
        matvec2(afr, vsel, h, y);
        npart(1, y);
        __syncthreads();
        float e1v = sqrtf(psum(1));
        float sc  = __builtin_amdgcn_rcpf(e1v + 1e-6f);
        vwrite(1, y, sc);
        eig = e1v;
        __syncthreads();
    }
    // ---- peeled iteration 2 (synchronous): u_2 = y_2/e_2, n_2 = 1 ----
    if (niter >= 2) {
        matvec2(afr, vsel + 512, h, y);
        npart(0, y);
        __syncthreads();
        float e2v = sqrtf(psum(0));
        float sc  = __builtin_amdgcn_rcpf(e2v + 1e-6f);
        vwrite(0, y, sc);
        eig = e2v;
        sc_m1 = sc;   // s_2
        nm2   = 1.0f; // n_1
        __syncthreads();
    }

    // ---- pipelined iterations 3..niter: one barrier each ----
    int wr = 0;
    for (int t = 3; t <= niter; ++t) {
        const int rd = wr;    // buffer holding u_{t-1}, part[rd] = q_{t-1}
        wr ^= 1;
        float q   = psum(rd);                                  // ||y_{t-1}||^2
        float e1v = __builtin_amdgcn_sqrtf(q);                 // e_{t-1}
        float nm1 = e1v * sc_m1;                               // n_{t-1}
        float sc  = nm2 * __builtin_amdgcn_rcpf(e1v * nm1 + 1e-12f);  // s_t
        matvec2(afr, vsel + (size_t)rd * 512, h, y);           // y_t
        vwrite(wr, y, sc);
        npart(wr, y);
        nm2 = nm1; sc_m1 = sc;
        __syncthreads();
    }

    // ---- epilogue: exact eig = ||y_T|| / n_{T-1}
    if (niter >= 3) {
        float qT = psum(wr);
        eig = sqrtf(qT) / (nm2 + 1e-12f);
    }
    if (tid == 0) out[b] = eig;
}

extern "C" void kernel_launch(void* const* d_in, const int* in_sizes, int n_in,
                              void* d_out, int out_size, void* d_ws, size_t ws_size,
                              hipStream_t stream) {
    const float* Are = (const float*)d_in[0];
    const float* Aim = (const float*)d_in[1];
    const float* vre = (const float*)d_in[2];
    const float* vim = (const float*)d_in[3];
    const int* niter = (const int*)d_in[4];
    float* out = (float*)d_out;

    f16* AhAre = (f16*)d_ws;                                            // 32 MB
    f16* AhAim = (f16*)((char*)d_ws + (size_t)32 * 1024 * 1024);        // 32 MB

    k_gemm<<<dim3(256), dim3(512), 0, stream>>>(Are, Aim, AhAre, AhAim);
    k_power<<<dim3(256), dim3(512), 0, stream>>>(AhAre, AhAim, vre, vim, niter, out);
}